// Round 1
// baseline (71.933 us; speedup 1.0000x reference)
//
#include <hip/hip_runtime.h>
#include <math.h>

#define SEQ 16384
#define EMB 16

// Kernel A: reduce x -> (xmin, xmax); compute a = wq.wk, c = bq.wk.
// ws layout (floats): [0]=a, [1]=c, [2]=xmin, [3]=xmax
__global__ __launch_bounds__(256) void prep_kernel(
    const float* __restrict__ x,
    const float* __restrict__ Wq,
    const float* __restrict__ Wk,
    const float* __restrict__ bq,
    float* __restrict__ ws) {
    __shared__ float smin[256];
    __shared__ float smax[256];
    const int tid = threadIdx.x;
    float vmin = 1e30f, vmax = -1e30f;
    const float4* x4 = (const float4*)x;
    for (int i = tid; i < SEQ / 4; i += 256) {
        float4 v = x4[i];
        vmin = fminf(vmin, fminf(fminf(v.x, v.y), fminf(v.z, v.w)));
        vmax = fmaxf(vmax, fmaxf(fmaxf(v.x, v.y), fmaxf(v.z, v.w)));
    }
    smin[tid] = vmin;
    smax[tid] = vmax;
    __syncthreads();
    for (int s = 128; s > 0; s >>= 1) {
        if (tid < s) {
            smin[tid] = fminf(smin[tid], smin[tid + s]);
            smax[tid] = fmaxf(smax[tid], smax[tid + s]);
        }
        __syncthreads();
    }
    if (tid == 0) {
        float a = 0.f, c = 0.f;
        for (int e = 0; e < EMB; ++e) {
            a += Wq[e] * Wk[e];
            c += bq[e] * Wk[e];
        }
        ws[0] = a;
        ws[1] = c;
        ws[2] = smin[0];
        ws[3] = smax[0];
    }
}

// Kernel B: one wave per row i. m_i = sum_j x_j exp(t_i x_j) / sum_j exp(t_i x_j)
// out[i][e] = Wv[e] * m_i + bv[e]
__global__ __launch_bounds__(256) void attn_kernel(
    const float* __restrict__ x,
    const float* __restrict__ Wv,
    const float* __restrict__ bv,
    const float* __restrict__ ws,
    float* __restrict__ out) {
    const int wave = threadIdx.x >> 6;
    const int lane = threadIdx.x & 63;
    const int row  = (blockIdx.x << 2) + wave;

    const float a    = ws[0];
    const float c    = ws[1];
    const float xmin = ws[2];
    const float xmax = ws[3];

    const float LOG2E = 1.4426950408889634f;
    const float xi = x[row];
    // t in log2 domain: logits_j = t2 * x_j  (base-2), constant terms cancel
    const float t2 = (a * xi + c) * 0.25f * LOG2E;
    const float mm = (t2 > 0.f) ? t2 * xmax : t2 * xmin;  // max_j t2*x_j

    float se = 0.f;  // sum exp
    float sx = 0.f;  // sum x*exp
    const float4* x4 = (const float4*)x;
    #pragma unroll 4
    for (int it = 0; it < SEQ / 256; ++it) {
        float4 v = x4[it * 64 + lane];
        float e0 = exp2f(t2 * v.x - mm);
        float e1 = exp2f(t2 * v.y - mm);
        float e2 = exp2f(t2 * v.z - mm);
        float e3 = exp2f(t2 * v.w - mm);
        se += (e0 + e1) + (e2 + e3);
        sx += (e0 * v.x + e1 * v.y) + (e2 * v.z + e3 * v.w);
    }
    // wave-wide butterfly reduction (64 lanes)
    #pragma unroll
    for (int off = 1; off < 64; off <<= 1) {
        se += __shfl_xor(se, off);
        sx += __shfl_xor(sx, off);
    }
    const float m = sx / se;
    if (lane < EMB) {
        out[row * EMB + lane] = Wv[lane] * m + bv[lane];
    }
}

extern "C" void kernel_launch(void* const* d_in, const int* in_sizes, int n_in,
                              void* d_out, int out_size, void* d_ws, size_t ws_size,
                              hipStream_t stream) {
    const float* x  = (const float*)d_in[0];
    const float* Wq = (const float*)d_in[1];
    const float* bq = (const float*)d_in[2];
    const float* Wk = (const float*)d_in[3];
    // d_in[4] = bk: cancels in softmax, unused
    const float* Wv = (const float*)d_in[5];
    const float* bv = (const float*)d_in[6];
    float* out = (float*)d_out;
    float* ws  = (float*)d_ws;

    prep_kernel<<<1, 256, 0, stream>>>(x, Wq, Wk, bq, ws);
    attn_kernel<<<SEQ / 4, 256, 0, stream>>>(x, Wv, bv, ws, out);
}

// Round 2
// 21.184 us; speedup vs baseline: 3.3956x; 3.3956x over previous
//
#include <hip/hip_runtime.h>
#include <math.h>

#define SEQ  16384
#define EMB  16
#define NTAB 4096
#define SCALE 0.3606737602222409f   // 0.25 * log2(e): logits_j = SCALE*(a*x_i+c)*x_j in base-2

#if __has_builtin(__builtin_amdgcn_exp2f)
#define EXP2(v) __builtin_amdgcn_exp2f(v)
#else
#define EXP2(v) exp2f(v)
#endif

// ws layout (floats): [0]=a, [1]=c, [2]=tlmin, [3]=invh, [16..16+NTAB)=m-table

// Kernel A: each block (4 waves) computes x-minmax cooperatively, then each wave
// computes one table point m(tl_k) = sum_j x_j*2^(tl_k*x_j) / sum_j 2^(tl_k*x_j).
__global__ __launch_bounds__(256) void table_kernel(
    const float* __restrict__ x,
    const float* __restrict__ Wq,
    const float* __restrict__ bq,
    const float* __restrict__ Wk,
    float* __restrict__ ws) {
    __shared__ float smin[256];
    __shared__ float smax[256];
    const int tid = threadIdx.x;
    const float4* x4 = (const float4*)x;

    float vmin = 1e30f, vmax = -1e30f;
    #pragma unroll
    for (int i = 0; i < 16; ++i) {
        float4 v = x4[tid + 256 * i];
        vmin = fminf(vmin, fminf(fminf(v.x, v.y), fminf(v.z, v.w)));
        vmax = fmaxf(vmax, fmaxf(fmaxf(v.x, v.y), fmaxf(v.z, v.w)));
    }
    smin[tid] = vmin;
    smax[tid] = vmax;
    __syncthreads();
    for (int s = 128; s > 0; s >>= 1) {
        if (tid < s) {
            smin[tid] = fminf(smin[tid], smin[tid + s]);
            smax[tid] = fmaxf(smax[tid], smax[tid + s]);
        }
        __syncthreads();
    }
    const float xmin = smin[0];
    const float xmax = smax[0];

    // a = wq.wk, c = bq.wk — uniform per-thread (L1-broadcast loads)
    float a = 0.f, c = 0.f;
    #pragma unroll
    for (int e = 0; e < EMB; ++e) {
        a = fmaf(Wq[e], Wk[e], a);
        c = fmaf(bq[e], Wk[e], c);
    }
    const float tl0 = (a * xmin + c) * SCALE;
    const float tl1 = (a * xmax + c) * SCALE;
    const float tlmin = fminf(tl0, tl1);
    const float span  = fmaxf(tl0, tl1) - tlmin;
    const float h     = span / (float)(NTAB - 1);

    const int wave = tid >> 6;
    const int lane = tid & 63;
    const int k    = (blockIdx.x << 2) + wave;
    const float tl = tlmin + h * (float)k;
    const float mm = (tl > 0.f) ? tl * xmax : tl * xmin;   // max_j tl*x_j (arg <= 0)

    float se = 0.f, sx = 0.f;
    #pragma unroll 4
    for (int it = 0; it < SEQ / 256; ++it) {
        float4 v = x4[it * 64 + lane];
        float e0 = EXP2(fmaf(tl, v.x, -mm));
        float e1 = EXP2(fmaf(tl, v.y, -mm));
        float e2 = EXP2(fmaf(tl, v.z, -mm));
        float e3 = EXP2(fmaf(tl, v.w, -mm));
        se += (e0 + e1) + (e2 + e3);
        sx = fmaf(e0, v.x, sx);
        sx = fmaf(e1, v.y, sx);
        sx = fmaf(e2, v.z, sx);
        sx = fmaf(e3, v.w, sx);
    }
    #pragma unroll
    for (int off = 1; off < 64; off <<= 1) {
        se += __shfl_xor(se, off);
        sx += __shfl_xor(sx, off);
    }
    if (lane == 0) ws[16 + k] = sx / se;
    if (blockIdx.x == 0 && tid == 0) {
        ws[0] = a;
        ws[1] = c;
        ws[2] = tlmin;
        ws[3] = (span > 0.f) ? (float)(NTAB - 1) / span : 0.f;
    }
}

// Kernel B: one thread per row: t_i -> lerp(table) -> m_i; then block-coalesced
// float4 writes of out[row][e] = Wv[e]*m + bv[e].
__global__ __launch_bounds__(256) void interp_kernel(
    const float* __restrict__ x,
    const float* __restrict__ Wv,
    const float* __restrict__ bv,
    const float* __restrict__ ws,
    float* __restrict__ out) {
    __shared__ float mrow[256];
    const int tid  = threadIdx.x;
    const int row0 = blockIdx.x * 256;

    const float a     = ws[0];
    const float c     = ws[1];
    const float tlmin = ws[2];
    const float invh  = ws[3];
    const float* T = ws + 16;

    const float xi = x[row0 + tid];
    const float tl = fmaf(a, xi, c) * SCALE;
    float u = (tl - tlmin) * invh;
    u = fminf(fmaxf(u, 0.f), (float)(NTAB - 1));
    int i0 = (int)u;
    if (i0 > NTAB - 2) i0 = NTAB - 2;
    const float fr = u - (float)i0;
    const float t0 = T[i0];
    const float t1 = T[i0 + 1];
    mrow[tid] = fmaf(fr, t1 - t0, t0);
    __syncthreads();

    const float4* Wv4 = (const float4*)Wv;
    const float4* bv4 = (const float4*)bv;
    float4* o4 = (float4*)(out + (size_t)row0 * EMB);
    #pragma unroll
    for (int i = 0; i < 4; ++i) {
        int k  = tid + 256 * i;       // float4 index in this block's 1024-float4 chunk
        int r  = k >> 2;              // row within block
        int e4 = k & 3;               // which float4 of the 16-wide embedding
        float m  = mrow[r];
        float4 w = Wv4[e4];
        float4 b = bv4[e4];
        float4 o;
        o.x = fmaf(w.x, m, b.x);
        o.y = fmaf(w.y, m, b.y);
        o.z = fmaf(w.z, m, b.z);
        o.w = fmaf(w.w, m, b.w);
        o4[k] = o;
    }
}

extern "C" void kernel_launch(void* const* d_in, const int* in_sizes, int n_in,
                              void* d_out, int out_size, void* d_ws, size_t ws_size,
                              hipStream_t stream) {
    const float* x  = (const float*)d_in[0];
    const float* Wq = (const float*)d_in[1];
    const float* bq = (const float*)d_in[2];
    const float* Wk = (const float*)d_in[3];
    // d_in[4] = bk: row-constant in logits, cancels in softmax
    const float* Wv = (const float*)d_in[5];
    const float* bv = (const float*)d_in[6];
    float* out = (float*)d_out;
    float* ws  = (float*)d_ws;

    table_kernel<<<NTAB / 4, 256, 0, stream>>>(x, Wq, bq, Wk, ws);
    interp_kernel<<<SEQ / 256, 256, 0, stream>>>(x, Wv, bv, ws, out);
}

// Round 3
// 19.353 us; speedup vs baseline: 3.7170x; 1.0946x over previous
//
#include <hip/hip_runtime.h>
#include <math.h>

#define SEQ  16384
#define EMB  16
#define NTAB 4096
#define SCALE 0.3606737602222409f   // 0.25 * log2(e): base-2 logits

#if __has_builtin(__builtin_amdgcn_exp2f)
#define EXP2(v) __builtin_amdgcn_exp2f(v)
#else
#define EXP2(v) exp2f(v)
#endif

// ws layout (floats): [0]=a, [1]=c, [2]=tlmin, [3]=invh, [16..16+NTAB)=m-table

// Each block: stage x (64KB) into LDS + cooperative minmax; then each of the
// 4 waves computes 2 table points per pass over LDS-resident x.
// Grid: NTAB/8 = 512 blocks -> 2 blocks/CU, 2 waves/SIMD.
__global__ __launch_bounds__(256) void table_kernel(
    const float* __restrict__ x,
    const float* __restrict__ Wq,
    const float* __restrict__ bq,
    const float* __restrict__ Wk,
    float* __restrict__ ws) {
    __shared__ float xs[SEQ];          // 64 KB
    __shared__ float smin[256];
    __shared__ float smax[256];
    const int tid = threadIdx.x;
    const float4* x4 = (const float4*)x;
    float4* xs4 = (float4*)xs;

    float vmin = 1e30f, vmax = -1e30f;
    #pragma unroll
    for (int i = 0; i < 16; ++i) {
        float4 v = x4[tid + 256 * i];
        xs4[tid + 256 * i] = v;
        vmin = fminf(vmin, fminf(fminf(v.x, v.y), fminf(v.z, v.w)));
        vmax = fmaxf(vmax, fmaxf(fmaxf(v.x, v.y), fmaxf(v.z, v.w)));
    }
    smin[tid] = vmin;
    smax[tid] = vmax;
    __syncthreads();
    for (int s = 128; s > 0; s >>= 1) {
        if (tid < s) {
            smin[tid] = fminf(smin[tid], smin[tid + s]);
            smax[tid] = fmaxf(smax[tid], smax[tid + s]);
        }
        __syncthreads();
    }
    const float xmin = smin[0];
    const float xmax = smax[0];

    // a = wq.wk, c = bq.wk — uniform scalar loads (L1-broadcast)
    float a = 0.f, c = 0.f;
    #pragma unroll
    for (int e = 0; e < EMB; ++e) {
        a = fmaf(Wq[e], Wk[e], a);
        c = fmaf(bq[e], Wk[e], c);
    }
    const float t0 = (a * xmin + c) * SCALE;
    const float t1 = (a * xmax + c) * SCALE;
    const float tlmin = fminf(t0, t1);
    const float span  = fmaxf(t0, t1) - tlmin;
    const float h     = span / (float)(NTAB - 1);

    const int wave = tid >> 6;
    const int lane = tid & 63;
    const int k0   = blockIdx.x * 8 + wave * 2;   // this wave's 2 table points

    const float tlA = tlmin + h * (float)k0;
    const float tlB = tlmin + h * (float)(k0 + 1);
    const float mmA = (tlA > 0.f) ? tlA * xmax : tlA * xmin;
    const float mmB = (tlB > 0.f) ? tlB * xmax : tlB * xmin;

    float seA = 0.f, sxA = 0.f, seB = 0.f, sxB = 0.f;
    #pragma unroll 4
    for (int it = 0; it < SEQ / 256; ++it) {
        float4 v = xs4[it * 64 + lane];
        float a0 = EXP2(fmaf(tlA, v.x, -mmA));
        float a1 = EXP2(fmaf(tlA, v.y, -mmA));
        float a2 = EXP2(fmaf(tlA, v.z, -mmA));
        float a3 = EXP2(fmaf(tlA, v.w, -mmA));
        float b0 = EXP2(fmaf(tlB, v.x, -mmB));
        float b1 = EXP2(fmaf(tlB, v.y, -mmB));
        float b2 = EXP2(fmaf(tlB, v.z, -mmB));
        float b3 = EXP2(fmaf(tlB, v.w, -mmB));
        seA += (a0 + a1) + (a2 + a3);
        seB += (b0 + b1) + (b2 + b3);
        sxA = fmaf(a0, v.x, sxA); sxA = fmaf(a1, v.y, sxA);
        sxA = fmaf(a2, v.z, sxA); sxA = fmaf(a3, v.w, sxA);
        sxB = fmaf(b0, v.x, sxB); sxB = fmaf(b1, v.y, sxB);
        sxB = fmaf(b2, v.z, sxB); sxB = fmaf(b3, v.w, sxB);
    }
    #pragma unroll
    for (int off = 1; off < 64; off <<= 1) {
        seA += __shfl_xor(seA, off);
        sxA += __shfl_xor(sxA, off);
        seB += __shfl_xor(seB, off);
        sxB += __shfl_xor(sxB, off);
    }
    if (lane == 0) {
        ws[16 + k0]     = sxA / seA;
        ws[16 + k0 + 1] = sxB / seB;
    }
    if (blockIdx.x == 0 && tid == 0) {
        ws[0] = a;
        ws[1] = c;
        ws[2] = tlmin;
        ws[3] = (span > 0.f) ? (float)(NTAB - 1) / span : 0.f;
    }
}

// One thread per row: t_i -> lerp(table) -> m_i; block-coalesced float4 output.
__global__ __launch_bounds__(256) void interp_kernel(
    const float* __restrict__ x,
    const float* __restrict__ Wv,
    const float* __restrict__ bv,
    const float* __restrict__ ws,
    float* __restrict__ out) {
    __shared__ float mrow[256];
    const int tid  = threadIdx.x;
    const int row0 = blockIdx.x * 256;

    const float a     = ws[0];
    const float c     = ws[1];
    const float tlmin = ws[2];
    const float invh  = ws[3];
    const float* T = ws + 16;

    const float xi = x[row0 + tid];
    const float tl = fmaf(a, xi, c) * SCALE;
    float u = (tl - tlmin) * invh;
    u = fminf(fmaxf(u, 0.f), (float)(NTAB - 1));
    int i0 = (int)u;
    if (i0 > NTAB - 2) i0 = NTAB - 2;
    const float fr = u - (float)i0;
    const float v0 = T[i0];
    const float v1 = T[i0 + 1];
    mrow[tid] = fmaf(fr, v1 - v0, v0);
    __syncthreads();

    const float4* Wv4 = (const float4*)Wv;
    const float4* bv4 = (const float4*)bv;
    float4* o4 = (float4*)(out + (size_t)row0 * EMB);
    #pragma unroll
    for (int i = 0; i < 4; ++i) {
        int k  = tid + 256 * i;
        int r  = k >> 2;
        int e4 = k & 3;
        float m  = mrow[r];
        float4 w = Wv4[e4];
        float4 b = bv4[e4];
        float4 o;
        o.x = fmaf(w.x, m, b.x);
        o.y = fmaf(w.y, m, b.y);
        o.z = fmaf(w.z, m, b.z);
        o.w = fmaf(w.w, m, b.w);
        o4[k] = o;
    }
}

extern "C" void kernel_launch(void* const* d_in, const int* in_sizes, int n_in,
                              void* d_out, int out_size, void* d_ws, size_t ws_size,
                              hipStream_t stream) {
    const float* x  = (const float*)d_in[0];
    const float* Wq = (const float*)d_in[1];
    const float* bq = (const float*)d_in[2];
    const float* Wk = (const float*)d_in[3];
    // d_in[4] = bk: row-constant in logits, cancels in softmax
    const float* Wv = (const float*)d_in[5];
    const float* bv = (const float*)d_in[6];
    float* out = (float*)d_out;
    float* ws  = (float*)d_ws;

    table_kernel<<<NTAB / 8, 256, 0, stream>>>(x, Wq, bq, Wk, ws);
    interp_kernel<<<SEQ / 256, 256, 0, stream>>>(x, Wv, bv, ws, out);
}

// Round 4
// 14.776 us; speedup vs baseline: 4.8681x; 1.3097x over previous
//
#include <hip/hip_runtime.h>
#include <math.h>

#define SEQ  16384
#define EMB  16
#define NBIN 1024                   // histogram bins (== block size)
#define NTHREADS 1024
#define ROWS_PER_BLOCK 64           // SEQ / 256 blocks
#define SCALE 0.3606737602222409f   // 0.25 * log2(e): base-2 logits

#if __has_builtin(__builtin_amdgcn_exp2f)
#define EXP2(v) __builtin_amdgcn_exp2f(v)
#else
#define EXP2(v) exp2f(v)
#endif

// One fused kernel. Each block (256 total, 1 per CU):
//  1. stage x into LDS, cooperative min/max
//  2. deterministic histogram of x (int LDS atomics: count + fixed-point sum)
//  3. per-bin mean -> (mu_b, n_b) in LDS, then hoisted to 16 bins/lane in VGPRs
//  4. 64 rows: t_i = SCALE*(a*x_i + c);
//     m_i = sum_b n_b*mu_b*2^(t*mu_b) / sum_b n_b*2^(t*mu_b)   (wave-reduced)
//  5. out[i][e] = Wv[e]*m_i + bv[e]   (coalesced 256B store per wave)
__global__ __launch_bounds__(NTHREADS) void attn_kernel(
    const float* __restrict__ x,
    const float* __restrict__ Wq,
    const float* __restrict__ bq,
    const float* __restrict__ Wk,
    const float* __restrict__ Wv,
    const float* __restrict__ bv,
    float* __restrict__ out) {

    __shared__ float  xs[SEQ];            // 64 KB
    __shared__ float  sred[2 * NTHREADS]; // 8 KB: [0..N)=min, [N..2N)=max
    __shared__ int    icnt[NBIN];         // 4 KB
    __shared__ int    isum[NBIN];         // 4 KB  (x scaled by 2^14, |sum| < 2^31)
    __shared__ float2 hs[NBIN];           // 8 KB: (mu, cnt)

    const int tid = threadIdx.x;

    // --- 1. stage + per-thread minmax ---
    const float4* x4 = (const float4*)x;
    float4* xs4 = (float4*)xs;
    float4 v[4];
    float vmin = 1e30f, vmax = -1e30f;
    #pragma unroll
    for (int k = 0; k < 4; ++k) {
        v[k] = x4[tid + NTHREADS * k];
        xs4[tid + NTHREADS * k] = v[k];
        vmin = fminf(vmin, fminf(fminf(v[k].x, v[k].y), fminf(v[k].z, v[k].w)));
        vmax = fmaxf(vmax, fmaxf(fmaxf(v[k].x, v[k].y), fmaxf(v[k].z, v[k].w)));
    }
    sred[tid] = vmin;
    sred[NTHREADS + tid] = vmax;
    icnt[tid] = 0;                 // NTHREADS == NBIN
    isum[tid] = 0;
    __syncthreads();
    for (int s = NTHREADS / 2; s > 0; s >>= 1) {
        if (tid < s) {
            sred[tid] = fminf(sred[tid], sred[tid + s]);
            sred[NTHREADS + tid] = fmaxf(sred[NTHREADS + tid], sred[NTHREADS + tid + s]);
        }
        __syncthreads();
    }
    const float xmin = sred[0];
    const float xmax = sred[NTHREADS];
    const float invw = (float)NBIN / (xmax - xmin + 1e-12f);

    // --- 2. deterministic histogram (int atomics) ---
    #pragma unroll
    for (int k = 0; k < 4; ++k) {
        const float* e = (const float*)&v[k];
        #pragma unroll
        for (int j = 0; j < 4; ++j) {
            const float xv = e[j];
            int b = (int)((xv - xmin) * invw);
            b = min(b, NBIN - 1);
            atomicAdd(&icnt[b], 1);
            atomicAdd(&isum[b], __float2int_rn(xv * 16384.0f));
        }
    }
    __syncthreads();

    // --- 3. bin means ---
    {
        const int c = icnt[tid];
        const float mu = (c > 0) ? ((float)isum[tid] * (1.0f / 16384.0f)) / (float)c
                                 : xmin;  // empty bin: in-range mu, weight 0
        hs[tid] = make_float2(mu, (float)c);
    }

    // --- 4. logit scalars (uniform, L1-broadcast loads) ---
    float a = 0.f, cc = 0.f;
    #pragma unroll
    for (int e = 0; e < EMB; ++e) {
        a  = fmaf(Wq[e], Wk[e], a);
        cc = fmaf(bq[e], Wk[e], cc);
    }
    const float pa = a * SCALE;
    const float pc = cc * SCALE;
    __syncthreads();

    // --- 5. hist -> registers: lane covers bins lane + 64*i ---
    const int wave = tid >> 6;
    const int lane = tid & 63;
    float mu[16], ct[16];
    #pragma unroll
    for (int i = 0; i < 16; ++i) {
        const float2 h = hs[i * 64 + lane];
        mu[i] = h.x;
        ct[i] = h.y;
    }

    // --- 6. rows: 4 per wave ---
    const int row0 = blockIdx.x * ROWS_PER_BLOCK + wave * 4;
    float mrow[4];
    #pragma unroll
    for (int r = 0; r < 4; ++r) {
        const float t  = fmaf(pa, xs[row0 + r], pc);
        const float mm = (t > 0.f) ? t * xmax : t * xmin;   // max_b t*mu_b, args <= 0
        float se = 0.f, sx = 0.f;
        #pragma unroll
        for (int i = 0; i < 16; ++i) {
            const float ev = EXP2(fmaf(t, mu[i], -mm));
            const float w  = ct[i] * ev;
            se += w;
            sx = fmaf(w, mu[i], sx);
        }
        #pragma unroll
        for (int off = 1; off < 64; off <<= 1) {
            se += __shfl_xor(se, off);
            sx += __shfl_xor(sx, off);
        }
        mrow[r] = sx / se;
    }

    // --- 7. output: wave writes 4 rows x 16 cols = 256 B contiguous ---
    const int rsel = lane >> 4;
    float m = mrow[0];
    m = (rsel == 1) ? mrow[1] : m;
    m = (rsel == 2) ? mrow[2] : m;
    m = (rsel == 3) ? mrow[3] : m;
    const int e = lane & 15;
    out[row0 * EMB + lane] = fmaf(Wv[e], m, bv[e]);
}

extern "C" void kernel_launch(void* const* d_in, const int* in_sizes, int n_in,
                              void* d_out, int out_size, void* d_ws, size_t ws_size,
                              hipStream_t stream) {
    const float* x  = (const float*)d_in[0];
    const float* Wq = (const float*)d_in[1];
    const float* bq = (const float*)d_in[2];
    const float* Wk = (const float*)d_in[3];
    // d_in[4] = bk: row-constant in logits, cancels in softmax
    const float* Wv = (const float*)d_in[5];
    const float* bv = (const float*)d_in[6];
    float* out = (float*)d_out;

    attn_kernel<<<SEQ / ROWS_PER_BLOCK, NTHREADS, 0, stream>>>(
        x, Wq, bq, Wk, Wv, bv, out);
}